// Round 4
// baseline (71.472 us; speedup 1.0000x reference)
//
#include <hip/hip_runtime.h>
#include <hip/hip_fp16.h>

// ---------------------------------------------------------------------------
// DotProductAttention: O = softmax((Q K^T / sqrt(128)) * p_q * p_k^T) V
// B=16, S=2048, D=128, fp32 in/out.
// Fold scale*p_q*log2(e) into Q, p_k into K (exact rank-1 folds), cast fp16,
// flash-attention with swapped-QK^T 32x32x16 MFMAs in log2-softmax domain.
// Round 4: 256-thread blocks (2 q-subtiles x 2 key-halves), q-tile 64,
// grid 512 -> TWO independent blocks/CU (decoupled barriers fill each
// other's stalls); split QK accumulator chains; tree-reduced softmax.
// ---------------------------------------------------------------------------

typedef _Float16 f16x8 __attribute__((ext_vector_type(8)));
typedef float f32x16 __attribute__((ext_vector_type(16)));
typedef unsigned int u32x4 __attribute__((ext_vector_type(4)));

#define S_LEN 2048
#define DD 128
#define TILE_BYTES 16384   // 64 keys x 128 d x 2B (one image tile)
#define NT 32              // kv tiles of 64 keys

#define EXP2(x) __builtin_amdgcn_exp2f(x)   // raw v_exp_f32 (2^x)

__device__ __forceinline__ unsigned int pk2(float a, float b) {
  __half2 h = __float22half2_rn(make_float2(a, b));
  return __builtin_bit_cast(unsigned int, h);
}

__device__ __forceinline__ void st8(void* dst, const float v[8]) {
  u32x4 u;
  u[0] = pk2(v[0], v[1]);
  u[1] = pk2(v[2], v[3]);
  u[2] = pk2(v[4], v[5]);
  u[3] = pk2(v[6], v[7]);
  *(u32x4*)dst = u;
}

__device__ __forceinline__ void gld16(const void* g, void* l) {
  __builtin_amdgcn_global_load_lds(
      (const __attribute__((address_space(1))) unsigned int*)g,
      (__attribute__((address_space(3))) unsigned int*)l, 16, 0, 0);
}

// --------------------------- pre-pass: Q --------------------------------
// Q' = fp16(Q * (log2e/sqrt(128)) * p_q[row]); row-major [B*S][128]
__global__ __launch_bounds__(256) void prep_q_k(const float* __restrict__ Q,
                                                const float* __restrict__ pq,
                                                char* __restrict__ qh) {
  size_t i = ((size_t)blockIdx.x * 256 + threadIdx.x) * 8;
  const float g = pq[i >> 7] * 0.12751743343158394f;  // (1/sqrt(128))*log2(e)
  float4 a = *(const float4*)(Q + i);
  float4 b = *(const float4*)(Q + i + 4);
  float v[8] = {a.x * g, a.y * g, a.z * g, a.w * g,
                b.x * g, b.y * g, b.z * g, b.w * g};
  st8(qh + i * 2, v);
}

// --------------------------- pre-pass: K,V images ------------------------
// K image tile (64x128): byte(key,d) = key*256 + ((2d) ^ ((key&7)<<4))
// V image tile:          byte(key,d) = d*128 + ((2key) ^ ((d&7)<<4))
__global__ __launch_bounds__(256) void prep_kv(
    const float* __restrict__ K, const float* __restrict__ V,
    const float* __restrict__ pk, char* __restrict__ kimg,
    char* __restrict__ vimg) {
  __shared__ float vt[64 * 132];
  const int t = threadIdx.x;
  const int bid = blockIdx.x;
  const int bq = bid & 15;
  const int kt = bid >> 4;
  const size_t rowbase = (size_t)bq * S_LEN + kt * 64;

  // stage V tile (fp32) into padded LDS for the transpose
#pragma unroll
  for (int cc = 0; cc < 8; ++cc) {
    const int f = cc * 256 + t;
    const int row = f >> 5;
    const int col = (f & 31) * 4;
    *(float4*)(vt + row * 132 + col) = *(const float4*)(V + (rowbase + row) * DD + col);
  }

  // K image: pure global->global, fold p_k
  char* kdst = kimg + (size_t)(bq * NT + kt) * TILE_BYTES;
#pragma unroll
  for (int cc = 0; cc < 4; ++cc) {
    const int p0 = (cc * 256 + t) * 16;
    const int key = p0 >> 8;
    const int d0 = ((p0 & 255) ^ ((key & 7) << 4)) >> 1;
    const float g = pk[rowbase + key];
    const float* src = K + (rowbase + key) * DD + d0;
    float4 a = *(const float4*)(src);
    float4 b = *(const float4*)(src + 4);
    float v[8] = {a.x * g, a.y * g, a.z * g, a.w * g,
                  b.x * g, b.y * g, b.z * g, b.w * g};
    st8(kdst + p0, v);
  }

  __syncthreads();

  // V image from LDS transpose
  char* vdst = vimg + (size_t)(bq * NT + kt) * TILE_BYTES;
#pragma unroll
  for (int cc = 0; cc < 4; ++cc) {
    const int p0 = (cc * 256 + t) * 16;
    const int dcol = p0 >> 7;
    const int key0 = ((p0 & 127) ^ ((dcol & 7) << 4)) >> 1;
    float v[8];
#pragma unroll
    for (int j = 0; j < 8; ++j) v[j] = vt[(key0 + j) * 132 + dcol];
    st8(vdst + p0, v);
  }
}

// --------------------------- main attention ------------------------------
// 256 threads = 4 waves: wid = qs*2 + ks; qs in [0,2) picks a 32-q subtile,
// ks in {0,1} picks the key-half of each 64-key tile (independent online
// softmax per key-half; partials merged in the epilogue through LDS).
// Grid 512 -> 2 independent blocks per CU (barrier-decoupled overlap).
__global__ __launch_bounds__(256, 2) void attn_main(const char* __restrict__ qh,
                                                    const char* __restrict__ kimg,
                                                    const char* __restrict__ vimg,
                                                    float* __restrict__ out) {
  __shared__ float4 ldsraw[4160];  // 66560 B: 2x32KB stage dbuf + 1KB ml (T aliases buf0)
  char* lds = (char*)ldsraw;
  const int tid = threadIdx.x;
  const int wid = tid >> 6;
  const int qs = wid >> 1;   // q subtile 0..1
  const int ks = wid & 1;    // key half 0..1
  const int lane = tid & 63;
  const int c = lane & 31;
  const int h = lane >> 5;
  const int swz = (c & 7) << 4;
  const int bid = blockIdx.x;
  const int bq = 2 * (bid & 7) + ((bid >> 3) & 1);  // batch pinned to XCD
  const int qt = bid >> 4;                          // q-tile (64 rows) 0..31
  const int q0 = qt * 64 + qs * 32;

  // Q fragments (B-operand of swapped QK^T): lane c = q row, 8 d's per kc
  f16x8 qf[8];
  const char* qrow = qh + (size_t)(bq * S_LEN + q0 + c) * (DD * 2);
#pragma unroll
  for (int kc = 0; kc < 8; ++kc) qf[kc] = *(const f16x8*)(qrow + kc * 32 + h * 16);

  f32x16 acc[4];
#pragma unroll
  for (int d = 0; d < 4; ++d) {
#pragma unroll
    for (int r = 0; r < 16; ++r) acc[d][r] = 0.f;
  }
  float m_run = -1.0e30f, l_run = 0.f;

  const char* kb = kimg + (size_t)bq * (NT * TILE_BYTES);
  const char* vb = vimg + (size_t)bq * (NT * TILE_BYTES);

  // prologue: stage tile 0 into buffer 0 (linear copy of pre-swizzled image)
#pragma unroll
  for (int j = 0; j < 4; ++j) {
    gld16(kb + j * 4096 + tid * 16, lds + j * 4096 + tid * 16);
    gld16(vb + j * 4096 + tid * 16, lds + TILE_BYTES + j * 4096 + tid * 16);
  }

  for (int kt = 0; kt < NT; ++kt) {
    __syncthreads();  // drains staging vmcnt; frees other buffer
    const int cur = (kt & 1) << 15;
    if (kt + 1 < NT) {
      const int nxt = ((kt + 1) & 1) << 15;
      const char* kn = kb + (size_t)(kt + 1) * TILE_BYTES;
      const char* vn = vb + (size_t)(kt + 1) * TILE_BYTES;
#pragma unroll
      for (int j = 0; j < 4; ++j) {
        gld16(kn + j * 4096 + tid * 16, lds + nxt + j * 4096 + tid * 16);
        gld16(vn + j * 4096 + tid * 16, lds + nxt + TILE_BYTES + j * 4096 + tid * 16);
      }
    }
    const char* kl = lds + cur;
    const char* vl = lds + cur + TILE_BYTES;

    // S^T = K' Q'^T over this wave's 32-key half; two independent MFMA chains
    f32x16 sa, sb;
#pragma unroll
    for (int r = 0; r < 16; ++r) { sa[r] = 0.f; sb[r] = 0.f; }
    __builtin_amdgcn_s_setprio(1);
#pragma unroll
    for (int kc = 0; kc < 4; ++kc) {
      f16x8 kfa = *(const f16x8*)(kl + (ks * 32 + c) * 256 + ((kc * 32 + h * 16) ^ swz));
      f16x8 kfb = *(const f16x8*)(kl + (ks * 32 + c) * 256 + (((kc + 4) * 32 + h * 16) ^ swz));
      sa = __builtin_amdgcn_mfma_f32_32x32x16_f16(kfa, qf[kc], sa, 0, 0, 0);
      sb = __builtin_amdgcn_mfma_f32_32x32x16_f16(kfb, qf[kc + 4], sb, 0, 0, 0);
    }
    __builtin_amdgcn_s_setprio(0);
    f32x16 s;
#pragma unroll
    for (int r = 0; r < 16; ++r) s[r] = sa[r] + sb[r];

    // lane-local online softmax (log2 domain; row q = c); tree reductions
    float m0 = fmaxf(s[0], s[1]), m1 = fmaxf(s[2], s[3]);
    float m2 = fmaxf(s[4], s[5]), m3 = fmaxf(s[6], s[7]);
    float m4 = fmaxf(s[8], s[9]), m5 = fmaxf(s[10], s[11]);
    float m6 = fmaxf(s[12], s[13]), m7 = fmaxf(s[14], s[15]);
    m0 = fmaxf(m0, m1); m2 = fmaxf(m2, m3); m4 = fmaxf(m4, m5); m6 = fmaxf(m6, m7);
    float cm = fmaxf(fmaxf(m0, m2), fmaxf(m4, m6));
    cm = fmaxf(cm, __shfl_xor(cm, 32));
    if (__any(cm > m_run + 11.0f)) {  // defer-max: rescale only on real growth
      const float mn = fmaxf(m_run, cm);
      const float al = EXP2(m_run - mn);
      m_run = mn;
      l_run *= al;
#pragma unroll
      for (int d = 0; d < 4; ++d) {
#pragma unroll
        for (int r = 0; r < 16; ++r) acc[d][r] *= al;
      }
    }
    float ps0 = 0.f, ps1 = 0.f;
#pragma unroll
    for (int r = 0; r < 8; ++r) {
      s[r] = EXP2(s[r] - m_run);       ps0 += s[r];
      s[r + 8] = EXP2(s[r + 8] - m_run); ps1 += s[r + 8];
    }
    l_run += ps0 + ps1;

    // PV: O^T += V^T P^T over the wave's two local 16-key chunks
#pragma unroll
    for (int kc = 0; kc < 2; ++kc) {
      const int A = kc * 8;
      const int Bb = A + 4;
      unsigned pA0 = pk2(s[A + 0], s[A + 1]);
      unsigned pA1 = pk2(s[A + 2], s[A + 3]);
      unsigned pB0 = pk2(s[Bb + 0], s[Bb + 1]);
      unsigned pB1 = pk2(s[Bb + 2], s[Bb + 3]);
      unsigned own0 = h ? pB0 : pA0;
      unsigned own1 = h ? pB1 : pA1;
      unsigned snd0 = h ? pA0 : pB0;
      unsigned snd1 = h ? pA1 : pB1;
      unsigned rcv0 = __shfl_xor(snd0, 32);
      unsigned rcv1 = __shfl_xor(snd1, 32);
      u32x4 pw;
      pw[0] = h ? rcv0 : own0;  // elems 0,1 (source half h=0)
      pw[1] = h ? rcv1 : own1;  // elems 2,3
      pw[2] = h ? own0 : rcv0;  // elems 4,5 (source half h=1)
      pw[3] = h ? own1 : rcv1;  // elems 6,7
      f16x8 pf = __builtin_bit_cast(f16x8, pw);
      const int kci = ks * 2 + kc;  // global 16-key chunk in tile
      __builtin_amdgcn_s_setprio(1);
#pragma unroll
      for (int d = 0; d < 4; ++d) {
        f16x8 vf = *(const f16x8*)(vl + (d * 32 + c) * 128 + ((kci * 32 + h * 16) ^ swz));
        acc[d] = __builtin_amdgcn_mfma_f32_32x32x16_f16(vf, pf, acc[d], 0, 0, 0);
      }
      __builtin_amdgcn_s_setprio(0);
    }
  }

  // ---- epilogue: merge the two key-half partials, transpose, store ----
  l_run += __shfl_xor(l_run, 32);  // full half-range sum for row q=c

  __syncthreads();  // all waves done with stage buffers
  float2* ml = (float2*)(lds + 65536);
  if (h == 0) ml[wid * 32 + c] = make_float2(m_run, l_run);
  __syncthreads();
  const float2 po = ml[(wid ^ 1) * 32 + c];  // partner key-half (same qs)
  const float ms = fmaxf(m_run, po.x);
  const float lstar = l_run * EXP2(m_run - ms) + po.y * EXP2(po.x - ms);
  const float w = EXP2(m_run - ms) / lstar;

  char* T = lds;  // 64 q x 128 d fp32 (32KB), swizzled rows
  if (ks == 0) {
#pragma unroll
    for (int d = 0; d < 4; ++d) {
#pragma unroll
      for (int rr = 0; rr < 4; ++rr) {
        const int dd = d * 32 + rr * 8 + h * 4;
        float4 v4;
        v4.x = acc[d][rr * 4 + 0] * w;
        v4.y = acc[d][rr * 4 + 1] * w;
        v4.z = acc[d][rr * 4 + 2] * w;
        v4.w = acc[d][rr * 4 + 3] * w;
        *(float4*)(T + (qs * 32 + c) * 512 + ((dd * 4) ^ swz)) = v4;
      }
    }
  }
  __syncthreads();
  if (ks == 1) {
#pragma unroll
    for (int d = 0; d < 4; ++d) {
#pragma unroll
      for (int rr = 0; rr < 4; ++rr) {
        const int dd = d * 32 + rr * 8 + h * 4;
        float4* p = (float4*)(T + (qs * 32 + c) * 512 + ((dd * 4) ^ swz));
        float4 t = *p;
        t.x += acc[d][rr * 4 + 0] * w;
        t.y += acc[d][rr * 4 + 1] * w;
        t.z += acc[d][rr * 4 + 2] * w;
        t.w += acc[d][rr * 4 + 3] * w;
        *p = t;
      }
    }
  }
  __syncthreads();

  float* obase = out + ((size_t)bq * S_LEN + qt * 64) * DD;
#pragma unroll
  for (int p = 0; p < 8; ++p) {
    const int idx = p * 256 + tid;
    const int q = idx >> 5;
    const int d0 = (idx & 31) * 4;
    float4 v4 = *(const float4*)(T + q * 512 + ((d0 * 4) ^ ((q & 7) << 4)));
    *(float4*)(obase + q * DD + d0) = v4;
  }
}

// --------------------------- launcher ------------------------------------
extern "C" void kernel_launch(void* const* d_in, const int* in_sizes, int n_in,
                              void* d_out, int out_size, void* d_ws, size_t ws_size,
                              hipStream_t stream) {
  const float* Q = (const float*)d_in[0];
  const float* K = (const float*)d_in[1];
  const float* V = (const float*)d_in[2];
  const float* pq = (const float*)d_in[3];
  const float* pk = (const float*)d_in[4];
  float* out = (float*)d_out;
  char* ws = (char*)d_ws;
  char* qh = ws;                         // 8 MB fp16 scaled Q (log2e folded)
  char* kimg = ws + (8u << 20);          // 8 MB K image (gated, swizzled)
  char* vimg = ws + (16u << 20);         // 8 MB V image (transposed, swizzled)

  prep_q_k<<<2048, 256, 0, stream>>>(Q, pq, qh);
  prep_kv<<<512, 256, 0, stream>>>(K, V, pk, kimg, vimg);
  attn_main<<<512, 256, 0, stream>>>(qh, kimg, vimg, out);
}